// Round 10
// baseline (311.434 us; speedup 1.0000x reference)
//
#include <hip/hip_runtime.h>
#include <hip/hip_bf16.h>
#include <hip/hip_fp16.h>

#define NS   100000
#define CIN  96
#define CHID 576
#define COUT 96
#define SPB  16              // sites per block in fused dw+proj
#define LDH  (CHID + 8)      // padded LDS row (halves)
#define ESPB 32              // sites per expand block
#define ELDH (CHID + 8)      // padded expand LDS row (halves)

typedef float    floatx4 __attribute__((ext_vector_type(4)));
typedef int      intx4   __attribute__((ext_vector_type(4)));
typedef short    short8  __attribute__((ext_vector_type(8)));
typedef _Float16 half8   __attribute__((ext_vector_type(8)));
typedef _Float16 half4   __attribute__((ext_vector_type(4)));

// ---------------------------------------------------------------------------
// K0: transpose+convert weights; zero dummy gather row x1h[NS]; w2 -> fp16.
// ---------------------------------------------------------------------------
__global__ void prep_kernel(const float* __restrict__ w1, const float* __restrict__ w3,
                            const float* __restrict__ w2,
                            unsigned short* __restrict__ w1T, _Float16* __restrict__ w3T,
                            _Float16* __restrict__ w2h, _Float16* __restrict__ x1h) {
  int i = blockIdx.x * blockDim.x + threadIdx.x;
  if (i >= CHID * CIN) return;
  if (i < CHID) x1h[(size_t)NS * CHID + i] = (_Float16)0.0f;
  if (i < 9 * CHID) w2h[i] = (_Float16)w2[i];  // ints <=127: exact
  {
    int h = i / CIN, k = i % CIN;  // w1T[h][k] = w1[k][h]
    w1T[i] = (unsigned short)(__float_as_uint(w1[k * CHID + h]) >> 16);
  }
  {
    int o = i / CHID, k = i % CHID;  // w3T[o][k] = w3[k][o]
    w3T[i] = (_Float16)w3[k * COUT + o];
  }
}

// ---------------------------------------------------------------------------
// K1: expand GEMM — BYTE-IDENTICAL to R9 (the 141us mystery being profiled).
// 256-thread (4-wave) blocks, 32 sites/block, wave w does ht tiles w*9..w*9+8,
// LDS-staged coalesced stores.
// ---------------------------------------------------------------------------
__global__ __launch_bounds__(256) void expand_kernel(
    const float* __restrict__ feats, const float* __restrict__ b1,
    const float* __restrict__ s1, const unsigned short* __restrict__ w1T,
    _Float16* __restrict__ x1h) {
  __shared__ _Float16 xt[ESPB * ELDH];
  const int t = threadIdx.x;
  const int lane = t & 63, wv = t >> 6;
  const int m = lane & 15, quad = lane >> 4;
  const int s0 = blockIdx.x * ESPB;

  short8 bfrag[2][3];
#pragma unroll
  for (int u = 0; u < 2; ++u) {
    const int site = s0 + u * 16 + m;
    const float* frow = feats + (size_t)site * CIN + quad * 8;
#pragma unroll
    for (int kc = 0; kc < 3; ++kc) {
      const float4 lo = *reinterpret_cast<const float4*>(frow + kc * 32);
      const float4 hi = *reinterpret_cast<const float4*>(frow + kc * 32 + 4);
      const float v[8] = {lo.x, lo.y, lo.z, lo.w, hi.x, hi.y, hi.z, hi.w};
#pragma unroll
      for (int j = 0; j < 8; ++j)
        bfrag[u][kc][j] = (short)(__float_as_uint(v[j]) >> 16);  // exact
    }
  }

  const int hq = quad * 4;
#pragma unroll 2
  for (int hi = 0; hi < 9; ++hi) {
    const int ht = wv * 9 + hi;
    const unsigned short* wrow = w1T + (ht * 16 + m) * CIN + quad * 8;
    short8 a[3];
#pragma unroll
    for (int kc = 0; kc < 3; ++kc)
      a[kc] = *reinterpret_cast<const short8*>(wrow + kc * 32);

    floatx4 acc[2] = {{0.f, 0.f, 0.f, 0.f}, {0.f, 0.f, 0.f, 0.f}};
#pragma unroll
    for (int kc = 0; kc < 3; ++kc)
#pragma unroll
      for (int u = 0; u < 2; ++u)
        acc[u] = __builtin_amdgcn_mfma_f32_16x16x32_bf16(a[kc], bfrag[u][kc], acc[u], 0, 0, 0);

    const floatx4 bv = *reinterpret_cast<const floatx4*>(b1 + ht * 16 + hq);
    const floatx4 sv = *reinterpret_cast<const floatx4*>(s1 + ht * 16 + hq);
    floatx4 sc;
#pragma unroll
    for (int j = 0; j < 4; ++j) sc[j] = rintf(sv[j]) * (1.0f / 256.0f);

#pragma unroll
    for (int u = 0; u < 2; ++u) {
      half4 r;
#pragma unroll
      for (int j = 0; j < 4; ++j) {
        float v = (acc[u][j] + bv[j]) * sc[j];
        r[j] = (_Float16)fminf(fmaxf(v, 0.0f), 6.0f);
      }
      *reinterpret_cast<half4*>(xt + (u * 16 + m) * ELDH + ht * 16 + hq) = r;
    }
  }
  __syncthreads();

  for (int j = t; j < ESPB * (CHID / 8); j += 256) {
    const int row = j / (CHID / 8), col = j - row * (CHID / 8);
    *reinterpret_cast<half8*>(x1h + (size_t)(s0 + row) * CHID + col * 8) =
        *reinterpret_cast<const half8*>(xt + row * ELDH + col * 8);
  }
}

// ---------------------------------------------------------------------------
// K2 (fused): dw 3x3 -> LDS -> proj MFMA -> out.  R6 form (153us best), plus
// an s0base arg: launched as TWO half-grid dispatches (~76us each) so the
// expand kernel surfaces in rocprof's top-5 (diagnostic for next round).
// ---------------------------------------------------------------------------
__global__ __launch_bounds__(256) void dwproj_kernel(
    const int* __restrict__ nbr, const _Float16* __restrict__ w2h,
    const float* __restrict__ b2, const float* __restrict__ s2,
    const _Float16* __restrict__ x1h, const _Float16* __restrict__ w3T,
    const float* __restrict__ feats, const float* __restrict__ b3,
    const float* __restrict__ s3, const float* __restrict__ s_main,
    const float* __restrict__ s_res, float* __restrict__ out, int s0base) {
  __shared__ _Float16 x2t[SPB * LDH];
  __shared__ _Float16 w2s[9 * CHID];
  __shared__ int offt[SPB * 12];   // per-site tap offsets (elements)
  const int t = threadIdx.x;
  const int s0 = s0base + blockIdx.x * SPB;

  if (t < SPB * 9) {
    const int k = t >> 4, n = t & 15;         // SPB = 16
    const int site = s0 + n;                   // NS % SPB == 0: always valid
    const int idx = nbr[k * NS + site];
    offt[n * 12 + k] = (idx < 0 ? NS : idx) * CHID;  // zero-row redirect
  }
  for (int j = t; j < 9 * CHID / 8; j += 256)  // stage w2 taps
    *reinterpret_cast<half8*>(w2s + j * 8) =
        *reinterpret_cast<const half8*>(w2h + j * 8);
  __syncthreads();

  // ---------------- DW phase ----------------
#pragma unroll 1
  for (int i = 0; i < 5; ++i) {
    const int w = i * 256 + t;
    if (w < SPB * 72) {
      const int n = w / 72, g = w - n * 72;
      const int c0 = g * 8;
      const intx4 oa = *reinterpret_cast<const intx4*>(offt + n * 12);
      const intx4 ob = *reinterpret_cast<const intx4*>(offt + n * 12 + 4);
      const int o8 = offt[n * 12 + 8];
      half8 v0 = *reinterpret_cast<const half8*>(x1h + (size_t)oa.x + c0);
      half8 v1 = *reinterpret_cast<const half8*>(x1h + (size_t)oa.y + c0);
      half8 v2 = *reinterpret_cast<const half8*>(x1h + (size_t)oa.z + c0);
      half8 v3 = *reinterpret_cast<const half8*>(x1h + (size_t)oa.w + c0);
      half8 v4 = *reinterpret_cast<const half8*>(x1h + (size_t)ob.x + c0);
      half8 v5 = *reinterpret_cast<const half8*>(x1h + (size_t)ob.y + c0);
      half8 v6 = *reinterpret_cast<const half8*>(x1h + (size_t)ob.z + c0);
      half8 v7 = *reinterpret_cast<const half8*>(x1h + (size_t)ob.w + c0);
      half8 v8 = *reinterpret_cast<const half8*>(x1h + (size_t)o8 + c0);
      float acc[8], scv[8];
      {
        const floatx4 ba = *reinterpret_cast<const floatx4*>(b2 + c0);
        const floatx4 bb = *reinterpret_cast<const floatx4*>(b2 + c0 + 4);
        const floatx4 sa = *reinterpret_cast<const floatx4*>(s2 + c0);
        const floatx4 sb = *reinterpret_cast<const floatx4*>(s2 + c0 + 4);
#pragma unroll
        for (int j = 0; j < 4; ++j) {
          acc[j] = ba[j];  acc[j + 4] = bb[j];
          scv[j] = rintf(sa[j]) * (1.0f / 256.0f);
          scv[j + 4] = rintf(sb[j]) * (1.0f / 256.0f);
        }
      }
      const half8 w0 = *reinterpret_cast<const half8*>(w2s + 0 * CHID + c0);
      const half8 w1v = *reinterpret_cast<const half8*>(w2s + 1 * CHID + c0);
      const half8 w2v = *reinterpret_cast<const half8*>(w2s + 2 * CHID + c0);
      const half8 w3v = *reinterpret_cast<const half8*>(w2s + 3 * CHID + c0);
      const half8 w4v = *reinterpret_cast<const half8*>(w2s + 4 * CHID + c0);
      const half8 w5v = *reinterpret_cast<const half8*>(w2s + 5 * CHID + c0);
      const half8 w6v = *reinterpret_cast<const half8*>(w2s + 6 * CHID + c0);
      const half8 w7v = *reinterpret_cast<const half8*>(w2s + 7 * CHID + c0);
      const half8 w8v = *reinterpret_cast<const half8*>(w2s + 8 * CHID + c0);
#pragma unroll
      for (int j = 0; j < 8; ++j) {
        acc[j] += (float)v0[j] * (float)w0[j];
        acc[j] += (float)v1[j] * (float)w1v[j];
        acc[j] += (float)v2[j] * (float)w2v[j];
        acc[j] += (float)v3[j] * (float)w3v[j];
        acc[j] += (float)v4[j] * (float)w4v[j];
        acc[j] += (float)v5[j] * (float)w5v[j];
        acc[j] += (float)v6[j] * (float)w6v[j];
        acc[j] += (float)v7[j] * (float)w7v[j];
        acc[j] += (float)v8[j] * (float)w8v[j];
      }
      half8 r;
#pragma unroll
      for (int j = 0; j < 8; ++j) {
        float v = acc[j] * scv[j];
        r[j] = (_Float16)fminf(fmaxf(v, 0.0f), 6.0f);
      }
      *reinterpret_cast<half8*>(x2t + n * LDH + c0) = r;
    }
  }
  __syncthreads();

  // ---------------- Proj phase (swapped: D[o][site]) ----------------
  const int wave = t >> 6, lane = t & 63;
  const int m = lane & 15, quad = lane >> 4;
  const float rsm = rintf(s_main[0]) * 256.0f;
  const float rsr = rintf(s_res[0]) * 256.0f;

  for (int tile = wave; tile < (SPB / 16) * (COUT / 16); tile += 4) {
    const int tm = tile / (COUT / 16);
    const int ot = tile % (COUT / 16);
    floatx4 acc = {0.f, 0.f, 0.f, 0.f};
    const _Float16* arow = w3T + (ot * 16 + m) * CHID + quad * 8;
    const _Float16* blds = x2t + (tm * 16 + m) * LDH + quad * 8;
#pragma unroll
    for (int kc = 0; kc < 18; ++kc) {
      const half8 a = *reinterpret_cast<const half8*>(arow + kc * 32);
      const half8 b = *reinterpret_cast<const half8*>(blds + kc * 32);
      acc = __builtin_amdgcn_mfma_f32_16x16x32_f16(a, b, acc, 0, 0, 0);
    }
    const int site = s0 + tm * 16 + m;
    if (site < NS) {
      const int o0 = ot * 16 + quad * 4;
      const floatx4 b3v = *reinterpret_cast<const floatx4*>(b3 + o0);
      const floatx4 s3v = *reinterpret_cast<const floatx4*>(s3 + o0);
      const floatx4 fv =
          *reinterpret_cast<const floatx4*>(feats + (size_t)site * COUT + o0);
      floatx4 r;
#pragma unroll
      for (int j = 0; j < 4; ++j) {
        float v = (acc[j] + b3v[j]) * (rintf(s3v[j]) * (1.0f / 256.0f));
        v = fminf(fmaxf(v, -128.0f), 128.0f);
        r[j] = rsm * v + rsr * fv[j];
      }
      *reinterpret_cast<floatx4*>(out + (size_t)site * COUT + o0) = r;
    }
  }
}

// ---------------------------------------------------------------------------
extern "C" void kernel_launch(void* const* d_in, const int* in_sizes, int n_in,
                              void* d_out, int out_size, void* d_ws, size_t ws_size,
                              hipStream_t stream) {
  const float* feats  = (const float*)d_in[0];
  const int*   nbr    = (const int*)d_in[1];
  const float* w1     = (const float*)d_in[2];
  const float* b1     = (const float*)d_in[3];
  const float* w2     = (const float*)d_in[4];
  const float* b2     = (const float*)d_in[5];
  const float* w3     = (const float*)d_in[6];
  const float* b3     = (const float*)d_in[7];
  const float* s1     = (const float*)d_in[8];
  const float* s2     = (const float*)d_in[9];
  const float* s3     = (const float*)d_in[10];
  const float* s_main = (const float*)d_in[11];
  const float* s_res  = (const float*)d_in[12];
  float* out = (float*)d_out;

  char* ws = (char*)d_ws;
  _Float16*       x1h = (_Float16*)ws;                      // (NS+1)*576 f16
  unsigned short* w1T = (unsigned short*)(ws + 115201152);  // 110,592 B
  _Float16*       w3T = (_Float16*)(ws + 115311744);        // 110,592 B
  _Float16*       w2h = (_Float16*)(ws + 115422336);        // 10,368 B

  prep_kernel<<<(CHID * CIN + 255) / 256, 256, 0, stream>>>(w1, w3, w2, w1T, w3T, w2h, x1h);
  expand_kernel<<<NS / ESPB, 256, 0, stream>>>(feats, b1, s1, w1T, x1h);
  const int half_blk = (NS / 2) / SPB;   // 3125 blocks per half
  dwproj_kernel<<<half_blk, 256, 0, stream>>>(nbr, w2h, b2, s2, x1h, w3T,
                                              feats, b3, s3, s_main, s_res, out, 0);
  dwproj_kernel<<<half_blk, 256, 0, stream>>>(nbr, w2h, b2, s2, x1h, w3T,
                                              feats, b3, s3, s_main, s_res, out, NS / 2);
}

// Round 11
// 292.350 us; speedup vs baseline: 1.0653x; 1.0653x over previous
//
#include <hip/hip_runtime.h>
#include <hip/hip_bf16.h>
#include <hip/hip_fp16.h>

#define NS   100000
#define CIN  96
#define CHID 576
#define COUT 96
#define SPB  16              // sites per block in fused dw+proj
#define LDH  (CHID + 8)      // padded LDS row (halves)
#define ESPB 32              // sites per expand block
#define ELDH (CHID + 8)      // padded expand LDS row (halves)
#define OFFMASK 0x7FFFFFF    // low 27 bits: idx*CHID (max 57.6M < 2^27)

typedef float    floatx4 __attribute__((ext_vector_type(4)));
typedef int      intx4   __attribute__((ext_vector_type(4)));
typedef short    short8  __attribute__((ext_vector_type(8)));
typedef _Float16 half8   __attribute__((ext_vector_type(8)));
typedef _Float16 half4   __attribute__((ext_vector_type(4)));

// ---------------------------------------------------------------------------
// K0: transpose+convert weights; zero dummy gather row x1h[NS]; w2 -> fp16.
// ---------------------------------------------------------------------------
__global__ void prep_kernel(const float* __restrict__ w1, const float* __restrict__ w3,
                            const float* __restrict__ w2,
                            unsigned short* __restrict__ w1T, _Float16* __restrict__ w3T,
                            _Float16* __restrict__ w2h, _Float16* __restrict__ x1h) {
  int i = blockIdx.x * blockDim.x + threadIdx.x;
  if (i >= CHID * CIN) return;
  if (i < CHID) x1h[(size_t)NS * CHID + i] = (_Float16)0.0f;
  if (i < 9 * CHID) w2h[i] = (_Float16)w2[i];  // ints <=127: exact
  {
    int h = i / CIN, k = i % CIN;  // w1T[h][k] = w1[k][h]
    w1T[i] = (unsigned short)(__float_as_uint(w1[k * CHID + h]) >> 16);
  }
  {
    int o = i / CHID, k = i % CHID;  // w3T[o][k] = w3[k][o]
    w3T[i] = (_Float16)w3[k * COUT + o];
  }
}

// ---------------------------------------------------------------------------
// K1: expand GEMM — unchanged from R9/R10 (~85-95us, rank-2 kernel).
// ---------------------------------------------------------------------------
__global__ __launch_bounds__(256) void expand_kernel(
    const float* __restrict__ feats, const float* __restrict__ b1,
    const float* __restrict__ s1, const unsigned short* __restrict__ w1T,
    _Float16* __restrict__ x1h) {
  __shared__ _Float16 xt[ESPB * ELDH];
  const int t = threadIdx.x;
  const int lane = t & 63, wv = t >> 6;
  const int m = lane & 15, quad = lane >> 4;
  const int s0 = blockIdx.x * ESPB;

  short8 bfrag[2][3];
#pragma unroll
  for (int u = 0; u < 2; ++u) {
    const int site = s0 + u * 16 + m;
    const float* frow = feats + (size_t)site * CIN + quad * 8;
#pragma unroll
    for (int kc = 0; kc < 3; ++kc) {
      const float4 lo = *reinterpret_cast<const float4*>(frow + kc * 32);
      const float4 hi = *reinterpret_cast<const float4*>(frow + kc * 32 + 4);
      const float v[8] = {lo.x, lo.y, lo.z, lo.w, hi.x, hi.y, hi.z, hi.w};
#pragma unroll
      for (int j = 0; j < 8; ++j)
        bfrag[u][kc][j] = (short)(__float_as_uint(v[j]) >> 16);  // exact
    }
  }

  const int hq = quad * 4;
#pragma unroll 2
  for (int hi = 0; hi < 9; ++hi) {
    const int ht = wv * 9 + hi;
    const unsigned short* wrow = w1T + (ht * 16 + m) * CIN + quad * 8;
    short8 a[3];
#pragma unroll
    for (int kc = 0; kc < 3; ++kc)
      a[kc] = *reinterpret_cast<const short8*>(wrow + kc * 32);

    floatx4 acc[2] = {{0.f, 0.f, 0.f, 0.f}, {0.f, 0.f, 0.f, 0.f}};
#pragma unroll
    for (int kc = 0; kc < 3; ++kc)
#pragma unroll
      for (int u = 0; u < 2; ++u)
        acc[u] = __builtin_amdgcn_mfma_f32_16x16x32_bf16(a[kc], bfrag[u][kc], acc[u], 0, 0, 0);

    const floatx4 bv = *reinterpret_cast<const floatx4*>(b1 + ht * 16 + hq);
    const floatx4 sv = *reinterpret_cast<const floatx4*>(s1 + ht * 16 + hq);
    floatx4 sc;
#pragma unroll
    for (int j = 0; j < 4; ++j) sc[j] = rintf(sv[j]) * (1.0f / 256.0f);

#pragma unroll
    for (int u = 0; u < 2; ++u) {
      half4 r;
#pragma unroll
      for (int j = 0; j < 4; ++j) {
        float v = (acc[u][j] + bv[j]) * sc[j];
        r[j] = (_Float16)fminf(fmaxf(v, 0.0f), 6.0f);
      }
      *reinterpret_cast<half4*>(xt + (u * 16 + m) * ELDH + ht * 16 + hq) = r;
    }
  }
  __syncthreads();

  for (int j = t; j < ESPB * (CHID / 8); j += 256) {
    const int row = j / (CHID / 8), col = j - row * (CHID / 8);
    *reinterpret_cast<half8*>(x1h + (size_t)(s0 + row) * CHID + col * 8) =
        *reinterpret_cast<const half8*>(xt + row * ELDH + col * 8);
  }
}

// ---------------------------------------------------------------------------
// K2 (fused): dw 3x3 -> LDS -> proj MFMA -> out.  R6 structure (152us) + TAP
// COMPACTION: only ~32.6% of neighbors are active, so on avg just 3.6 of 9
// taps are real; the rest were zero-row loads + FMAs on guaranteed zeros
// (60% wasted issue slots / VALU).  Setup builds a per-site compacted list
// of (offset | k<<27); the dw loop issues and consumes only cnt taps
// (whole-wave execz skip beyond cnt).  Exact: skipped taps contribute 0.
// Single dispatch again (R10's half-split cost +21us in tails).
// ---------------------------------------------------------------------------
__global__ __launch_bounds__(256) void dwproj_kernel(
    const int* __restrict__ nbr, const _Float16* __restrict__ w2h,
    const float* __restrict__ b2, const float* __restrict__ s2,
    const _Float16* __restrict__ x1h, const _Float16* __restrict__ w3T,
    const float* __restrict__ feats, const float* __restrict__ b3,
    const float* __restrict__ s3, const float* __restrict__ s_main,
    const float* __restrict__ s_res, float* __restrict__ out) {
  __shared__ _Float16 x2t[SPB * LDH];
  __shared__ _Float16 w2s[9 * CHID];
  __shared__ int offt[SPB * 12];   // compacted packed taps: idx*CHID | k<<27
  __shared__ int scnt[SPB];        // valid-tap count per site
  const int t = threadIdx.x;
  const int s0 = blockIdx.x * SPB;

  if (t < SPB) scnt[t] = 0;
  for (int j = t; j < 9 * CHID / 8; j += 256)  // stage w2 taps
    *reinterpret_cast<half8*>(w2s + j * 8) =
        *reinterpret_cast<const half8*>(w2h + j * 8);
  __syncthreads();
  if (t < SPB * 9) {
    const int k = t >> 4, n = t & 15;          // SPB = 16
    const int idx = nbr[k * NS + s0 + n];
    if (idx >= 0) {                             // compact valid taps only
      const int p = atomicAdd(&scnt[n], 1);
      offt[n * 12 + p] = idx * CHID + (k << 27);
    }
  }
  __syncthreads();

  // ---------------- DW phase (compacted) ----------------
#pragma unroll 1
  for (int i = 0; i < 5; ++i) {
    const int w = i * 256 + t;
    if (w < SPB * 72) {
      const int n = w / 72, g = w - n * 72;
      const int c0 = g * 8;
      const int cnt = scnt[n];                 // >=1 (center always valid)
      const int* op = offt + n * 12;
      half8 v[9];
      int kk[9];
      // batch-issue only the valid gathers (execz skip beyond cnt)
#pragma unroll
      for (int j = 0; j < 9; ++j)
        if (j < cnt) {
          const int pk = op[j];
          kk[j] = pk >> 27;
          v[j] = *reinterpret_cast<const half8*>(x1h + (size_t)(pk & OFFMASK) + c0);
        }
      float acc[8], scv[8];
      {
        const floatx4 ba = *reinterpret_cast<const floatx4*>(b2 + c0);
        const floatx4 bb = *reinterpret_cast<const floatx4*>(b2 + c0 + 4);
        const floatx4 sa = *reinterpret_cast<const floatx4*>(s2 + c0);
        const floatx4 sb = *reinterpret_cast<const floatx4*>(s2 + c0 + 4);
#pragma unroll
        for (int j = 0; j < 4; ++j) {
          acc[j] = ba[j];  acc[j + 4] = bb[j];
          scv[j] = rintf(sa[j]) * (1.0f / 256.0f);
          scv[j + 4] = rintf(sb[j]) * (1.0f / 256.0f);
        }
      }
      // consume only valid taps; w2 row picked by the tap's k from LDS
#pragma unroll
      for (int j = 0; j < 9; ++j)
        if (j < cnt) {
          const half8 wv = *reinterpret_cast<const half8*>(w2s + kk[j] * CHID + c0);
#pragma unroll
          for (int q = 0; q < 8; ++q)
            acc[q] += (float)v[j][q] * (float)wv[q];
        }
      half8 r;
#pragma unroll
      for (int j = 0; j < 8; ++j) {
        float vv = acc[j] * scv[j];
        r[j] = (_Float16)fminf(fmaxf(vv, 0.0f), 6.0f);
      }
      *reinterpret_cast<half8*>(x2t + n * LDH + c0) = r;
    }
  }
  __syncthreads();

  // ---------------- Proj phase (swapped: D[o][site]) ----------------
  const int wave = t >> 6, lane = t & 63;
  const int m = lane & 15, quad = lane >> 4;
  const float rsm = rintf(s_main[0]) * 256.0f;
  const float rsr = rintf(s_res[0]) * 256.0f;

  for (int tile = wave; tile < (SPB / 16) * (COUT / 16); tile += 4) {
    const int tm = tile / (COUT / 16);
    const int ot = tile % (COUT / 16);
    floatx4 acc = {0.f, 0.f, 0.f, 0.f};
    const _Float16* arow = w3T + (ot * 16 + m) * CHID + quad * 8;
    const _Float16* blds = x2t + (tm * 16 + m) * LDH + quad * 8;
#pragma unroll
    for (int kc = 0; kc < 18; ++kc) {
      const half8 a = *reinterpret_cast<const half8*>(arow + kc * 32);
      const half8 b = *reinterpret_cast<const half8*>(blds + kc * 32);
      acc = __builtin_amdgcn_mfma_f32_16x16x32_f16(a, b, acc, 0, 0, 0);
    }
    const int site = s0 + tm * 16 + m;
    if (site < NS) {
      const int o0 = ot * 16 + quad * 4;
      const floatx4 b3v = *reinterpret_cast<const floatx4*>(b3 + o0);
      const floatx4 s3v = *reinterpret_cast<const floatx4*>(s3 + o0);
      const floatx4 fv =
          *reinterpret_cast<const floatx4*>(feats + (size_t)site * COUT + o0);
      floatx4 r;
#pragma unroll
      for (int j = 0; j < 4; ++j) {
        float v = (acc[j] + b3v[j]) * (rintf(s3v[j]) * (1.0f / 256.0f));
        v = fminf(fmaxf(v, -128.0f), 128.0f);
        r[j] = rsm * v + rsr * fv[j];
      }
      *reinterpret_cast<floatx4*>(out + (size_t)site * COUT + o0) = r;
    }
  }
}

// ---------------------------------------------------------------------------
extern "C" void kernel_launch(void* const* d_in, const int* in_sizes, int n_in,
                              void* d_out, int out_size, void* d_ws, size_t ws_size,
                              hipStream_t stream) {
  const float* feats  = (const float*)d_in[0];
  const int*   nbr    = (const int*)d_in[1];
  const float* w1     = (const float*)d_in[2];
  const float* b1     = (const float*)d_in[3];
  const float* w2     = (const float*)d_in[4];
  const float* b2     = (const float*)d_in[5];
  const float* w3     = (const float*)d_in[6];
  const float* b3     = (const float*)d_in[7];
  const float* s1     = (const float*)d_in[8];
  const float* s2     = (const float*)d_in[9];
  const float* s3     = (const float*)d_in[10];
  const float* s_main = (const float*)d_in[11];
  const float* s_res  = (const float*)d_in[12];
  float* out = (float*)d_out;

  char* ws = (char*)d_ws;
  _Float16*       x1h = (_Float16*)ws;                      // (NS+1)*576 f16
  unsigned short* w1T = (unsigned short*)(ws + 115201152);  // 110,592 B
  _Float16*       w3T = (_Float16*)(ws + 115311744);        // 110,592 B
  _Float16*       w2h = (_Float16*)(ws + 115422336);        // 10,368 B

  prep_kernel<<<(CHID * CIN + 255) / 256, 256, 0, stream>>>(w1, w3, w2, w1T, w3T, w2h, x1h);
  expand_kernel<<<NS / ESPB, 256, 0, stream>>>(feats, b1, s1, w1T, x1h);
  const int nblk = (NS + SPB - 1) / SPB;
  dwproj_kernel<<<nblk, 256, 0, stream>>>(nbr, w2h, b2, s2, x1h, w3T,
                                          feats, b3, s3, s_main, s_res, out);
}